// Round 4
// baseline (987.532 us; speedup 1.0000x reference)
//
#include <hip/hip_runtime.h>

// Fused 3-branch shared LSTM(H1=3) -> LSTM(H2=9) -> dense(3)+sigmoid, T=2048, B=1024.
// 9 lanes per chain (lane u: LSTM1 unit (u/3,u%3), LSTM2 unit u), 7 chains/wave.
// Weights in VGPRs pre-scaled by -log2(e); merged-rcp sigmoid cells; scaled cell state.
// Per-lane ROTATED gather order (slot k = unit (3p+k)%9): own branch lands in slots 0..2
// (no cndmask selects); LSTM2/dense weights loaded in the matching permutation.
// R4: KC=28 chunks, WARMUP=64 (4116 waves = 4/SIMD to fill stall cycles).

#define BATCH  1024
#define SEQT   2048
#define KC     28
#define WPC    147    // ceil(1024/7) waves per chunk slot
#define WARMUP 64

__device__ __forceinline__ float fexp2(float v) { return __builtin_amdgcn_exp2f(v); }
__device__ __forceinline__ float frcp(float v)  { return __builtin_amdgcn_rcpf(v); }
__device__ __forceinline__ float bperm(int addr, float v) {
    return __int_as_float(__builtin_amdgcn_ds_bpermute(addr, __float_as_int(v)));
}

__global__ __launch_bounds__(256, 4)
void fused_lstm3(const float* __restrict__ x,
                 const float* __restrict__ wk1, const float* __restrict__ wr1,
                 const float* __restrict__ b1,
                 const float* __restrict__ wk2, const float* __restrict__ wr2,
                 const float* __restrict__ b2,
                 const float* __restrict__ wdn, const float* __restrict__ bdn,
                 float* __restrict__ out)
{
    const int lane  = threadIdx.x & 63;
    const int wavei = threadIdx.x >> 6;
    const int group = lane / 9;                  // 7 groups of 9 lanes; lane 63 idle
    const bool act  = (group < 7);
    const int u     = act ? (lane - group * 9) : 0;

    const int wv = blockIdx.x * 4 + wavei;
    int s        = wv / WPC;
    const int bw = wv - s * WPC;
    const bool vs = (s < KC);
    if (!vs) s = KC - 1;
    int b = bw * 7 + (act ? group : 6);
    const bool vb = (b < BATCH);
    if (!vb) b = BATCH - 1;
    const bool do_store = vs && vb && act && (u < 3);

    const int t_start = (SEQT * s) / KC;
    const int t_end   = (SEQT * (s + 1)) / KC;
    const int t0      = (t_start > WARMUP) ? (t_start - WARMUP) : 0;

    const int p  = u / 3;                        // branch index
    const int q  = u - p * 3;                    // unit within branch

    const float SS = -1.44269504088896f;         // -log2(e) folded into gate weights

    // rotated gather addresses: slot k <- unit (3p+k)%9 of this group
    int offv[9];
#pragma unroll
    for (int k = 0; k < 9; ++k) {
        int j = 3 * p + k; j = (j >= 9) ? j - 9 : j;
        offv[k] = (group * 9 + j) << 2;
    }

    // ---- per-lane weights in registers (pre-scaled, rotation-permuted) ----
    float w1xa[4], w1xb[4], w1h[4][3], b1g[4];
    float w2x[4][9], w2h[4][9], b2g[4];
    float wdk[9], dbu;
#pragma unroll
    for (int g = 0; g < 4; ++g) {
        const int c1 = g * 3 + q;                // gate-major: i,f,g,o
        w1xa[g] = wk1[c1] * SS;
        w1xb[g] = wk1[12 + c1] * SS;
#pragma unroll
        for (int k = 0; k < 3; ++k) w1h[g][k] = wr1[k * 12 + c1] * SS;
        b1g[g] = b1[c1] * SS;
        const int c2 = g * 9 + u;
#pragma unroll
        for (int k = 0; k < 9; ++k) {
            const int j = offv[k] >> 2;          // group*9 + unit
            const int jj = j - group * 9;        // permuted unit index
            w2x[g][k] = wk2[jj * 36 + c2] * SS;
            w2h[g][k] = wr2[jj * 36 + c2] * SS;
        }
        b2g[g] = b2[c2] * SS;
    }
    {
        const int d = (u < 3) ? u : 0;
#pragma unroll
        for (int k = 0; k < 9; ++k) {
            const int jj = (offv[k] >> 2) - group * 9;
            wdk[k] = wdn[jj * 3 + d] * SS;
        }
        dbu = bdn[d] * SS;
    }

    // ---- state ----
    float cm1 = 0.f, cm2 = 0.f;                  // scaled cell states (-log2e * c)
    float y4g[9], h2g[9];
#pragma unroll
    for (int k = 0; k < 9; ++k) { y4g[k] = 0.f; h2g[k] = 0.f; }

    const float* xp0 = x + ((size_t)b * SEQT + t0) * 6 + 2 * p;
    float*       op  = out + ((size_t)b * SEQT + t_start) * 3 + u;

    // depth-2 prefetch ring (chunk length >= 73, so +12 is safe)
    float2 xv0 = *(const float2*)(xp0);
    float2 xv1 = *(const float2*)(xp0 + 6);
    const float* xpf = xp0 + 12;

#pragma unroll 2
    for (int t = t0; t < t_end; ++t) {
        // prefetch x for t+2 (pointer freezes near chunk end)
        const float2 xn = *(const float2*)(xpf);
        xpf += ((t + 3) < t_end) ? 6 : 0;

        // ---- LSTM-1 (slots 0..2 are this lane's branch h) ----
        float z1g[4];
#pragma unroll
        for (int g = 0; g < 4; ++g) {
            const float za = b1g[g] + xv0.x * w1xa[g] + xv0.y * w1xb[g];
            const float zb = y4g[0] * w1h[g][0] + y4g[1] * w1h[g][1] + y4g[2] * w1h[g][2];
            z1g[g] = za + zb;
        }
        {
            const float eI = fexp2(z1g[0]), eF = fexp2(z1g[1]);
            const float eG = fexp2(z1g[2]), eO = fexp2(z1g[3]);
            const float f   = frcp(1.0f + eF);
            const float pig = (1.0f + eI) * (1.0f + eG);
            cm1 = f * cm1 + frcp(-0.69314718056f * pig);
            const float ec = fexp2(cm1);
            const float h1v = frcp((1.0f + eO) * (1.0f + ec));

            // ---- issue y4 gathers immediately (rotated order) ----
#pragma unroll
            for (int k = 0; k < 9; ++k) y4g[k] = bperm(offv[k], h1v);
        }

        // ---- dense + store for step t-1 (old h2g; fills DS window) ----
        if (t > t_start) {
            float a0 = dbu, a1 = 0.f;
#pragma unroll
            for (int k = 0; k < 4; ++k) a0 += h2g[k] * wdk[k];
#pragma unroll
            for (int k = 4; k < 9; ++k) a1 += h2g[k] * wdk[k];
            const float yv = frcp(1.0f + fexp2(a0 + a1));
            if (do_store) *op = yv;
            op += 3;
        }

        // ---- zh: LSTM2 h-recurrence partials (old h2g; fills DS window) ----
        float zh[4];
#pragma unroll
        for (int g = 0; g < 4; ++g) {
            float a0 = b2g[g], a1 = 0.f;
#pragma unroll
            for (int k = 0; k < 4; ++k) a0 += h2g[k] * w2h[g][k];
#pragma unroll
            for (int k = 4; k < 9; ++k) a1 += h2g[k] * w2h[g][k];
            zh[g] = a0 + a1;
        }

        // ---- finish LSTM2 (waits on y4 gathers here) ----
        float z2g[4];
#pragma unroll
        for (int g = 0; g < 4; ++g) {
            float a0 = 0.f, a1 = 0.f;
#pragma unroll
            for (int k = 0; k < 4; ++k) a0 += y4g[k] * w2x[g][k];
#pragma unroll
            for (int k = 4; k < 9; ++k) a1 += y4g[k] * w2x[g][k];
            z2g[g] = zh[g] + a0 + a1;
        }
        {
            const float eI = fexp2(z2g[0]), eF = fexp2(z2g[1]);
            const float eG = fexp2(z2g[2]), eO = fexp2(z2g[3]);
            const float f   = frcp(1.0f + eF);
            const float pig = (1.0f + eI) * (1.0f + eG);
            cm2 = f * cm2 + frcp(-0.69314718056f * pig);
            const float ec = fexp2(cm2);
            const float h2v = frcp((1.0f + eO) * (1.0f + ec));

            // ---- issue h2 gathers immediately ----
#pragma unroll
            for (int k = 0; k < 9; ++k) h2g[k] = bperm(offv[k], h2v);
        }

        xv0 = xv1; xv1 = xn;
    }

    // ---- epilogue: dense + store for final step (t_end-1) ----
    {
        float a0 = dbu, a1 = 0.f;
#pragma unroll
        for (int k = 0; k < 4; ++k) a0 += h2g[k] * wdk[k];
#pragma unroll
        for (int k = 4; k < 9; ++k) a1 += h2g[k] * wdk[k];
        const float yv = frcp(1.0f + fexp2(a0 + a1));
        if (do_store) *op = yv;
    }
}

extern "C" void kernel_launch(void* const* d_in, const int* in_sizes, int n_in,
                              void* d_out, int out_size, void* d_ws, size_t ws_size,
                              hipStream_t stream) {
    (void)in_sizes; (void)n_in; (void)d_ws; (void)ws_size; (void)out_size;
    const int blocks = (KC * WPC + 3) / 4;   // 1029 blocks x 4 waves = 4116 waves
    hipLaunchKernelGGL(fused_lstm3, dim3(blocks), dim3(256), 0, stream,
                       (const float*)d_in[0],
                       (const float*)d_in[1], (const float*)d_in[2], (const float*)d_in[3],
                       (const float*)d_in[4], (const float*)d_in[5], (const float*)d_in[6],
                       (const float*)d_in[7], (const float*)d_in[8],
                       (float*)d_out);
}

// Round 5
// 242.453 us; speedup vs baseline: 4.0731x; 4.0731x over previous
//
#include <hip/hip_runtime.h>

// Fused 3-branch shared LSTM(H1=3) -> LSTM(H2=9) -> dense(3)+sigmoid, T=2048, B=1024.
// 9 lanes per chain (lane u: LSTM1 unit (u/3,u%3), LSTM2 unit u), 7 chains/wave.
// Weights in VGPRs pre-scaled by -log2(e); merged-rcp sigmoid cells; scaled cell state.
// Rotated gather order (slot k = unit (3p+k)%9) so slots 0..2 are own-branch h.
// R5: amdgpu_waves_per_eu(3) for a 170-VGPR cap (no scratch/AGPR spill), KC=20
// (2940 waves ~ 2.9/SIMD resident), gate math packed as f32x2 -> v_pk_fma_f32.

#define BATCH  1024
#define SEQT   2048
#define KC     20
#define WPC    147    // ceil(1024/7) waves per chunk slot
#define WARMUP 64

typedef float f32x2 __attribute__((ext_vector_type(2)));

__device__ __forceinline__ float fexp2(float v) { return __builtin_amdgcn_exp2f(v); }
__device__ __forceinline__ float frcp(float v)  { return __builtin_amdgcn_rcpf(v); }
__device__ __forceinline__ float bperm(int addr, float v) {
    return __int_as_float(__builtin_amdgcn_ds_bpermute(addr, __float_as_int(v)));
}

__global__ __launch_bounds__(256) __attribute__((amdgpu_waves_per_eu(3)))
void fused_lstm3(const float* __restrict__ x,
                 const float* __restrict__ wk1, const float* __restrict__ wr1,
                 const float* __restrict__ b1,
                 const float* __restrict__ wk2, const float* __restrict__ wr2,
                 const float* __restrict__ b2,
                 const float* __restrict__ wdn, const float* __restrict__ bdn,
                 float* __restrict__ out)
{
    const int lane  = threadIdx.x & 63;
    const int wavei = threadIdx.x >> 6;
    const int group = lane / 9;                  // 7 groups of 9 lanes; lane 63 idle
    const bool act  = (group < 7);
    const int u     = act ? (lane - group * 9) : 0;

    const int wv = blockIdx.x * 4 + wavei;
    int s        = wv / WPC;
    const int bw = wv - s * WPC;
    const bool vs = (s < KC);
    if (!vs) s = KC - 1;
    int b = bw * 7 + (act ? group : 6);
    const bool vb = (b < BATCH);
    if (!vb) b = BATCH - 1;
    const bool do_store = vs && vb && act && (u < 3);

    const int t_start = (SEQT * s) / KC;
    const int t_end   = (SEQT * (s + 1)) / KC;
    const int t0      = (t_start > WARMUP) ? (t_start - WARMUP) : 0;

    const int p  = u / 3;                        // branch index
    const int q  = u - p * 3;                    // unit within branch

    const float SS = -1.44269504088896f;         // -log2(e) folded into gate weights

    // rotated gather addresses: slot k <- unit (3p+k)%9 of this group
    int offv[9];
#pragma unroll
    for (int k = 0; k < 9; ++k) {
        int j = 3 * p + k; j = (j >= 9) ? j - 9 : j;
        offv[k] = (group * 9 + j) << 2;
    }

    // ---- per-lane weights, pre-scaled, packed in gate-pairs (i,f) and (g,o) ----
    f32x2 w1a[2], w1b[2], w1h[2][3], b1p[2];
    f32x2 w2xp[2][9], w2hp[2][9], b2p[2];
    float wdk[9], dbu;
#pragma unroll
    for (int pr = 0; pr < 2; ++pr) {
        const int g0 = 2 * pr, g1 = 2 * pr + 1;
        const int c0 = g0 * 3 + q, c1 = g1 * 3 + q;      // LSTM1 cols (gate-major i,f,g,o)
        w1a[pr].x = wk1[c0] * SS;       w1a[pr].y = wk1[c1] * SS;
        w1b[pr].x = wk1[12 + c0] * SS;  w1b[pr].y = wk1[12 + c1] * SS;
#pragma unroll
        for (int k = 0; k < 3; ++k) {
            w1h[pr][k].x = wr1[k * 12 + c0] * SS;
            w1h[pr][k].y = wr1[k * 12 + c1] * SS;
        }
        b1p[pr].x = b1[c0] * SS;  b1p[pr].y = b1[c1] * SS;
        const int d0 = g0 * 9 + u, d1 = g1 * 9 + u;      // LSTM2 cols
#pragma unroll
        for (int k = 0; k < 9; ++k) {
            const int jj = (offv[k] >> 2) - group * 9;   // permuted unit index
            w2xp[pr][k].x = wk2[jj * 36 + d0] * SS;
            w2xp[pr][k].y = wk2[jj * 36 + d1] * SS;
            w2hp[pr][k].x = wr2[jj * 36 + d0] * SS;
            w2hp[pr][k].y = wr2[jj * 36 + d1] * SS;
        }
        b2p[pr].x = b2[d0] * SS;  b2p[pr].y = b2[d1] * SS;
    }
    {
        const int d = (u < 3) ? u : 0;
#pragma unroll
        for (int k = 0; k < 9; ++k) {
            const int jj = (offv[k] >> 2) - group * 9;
            wdk[k] = wdn[jj * 3 + d] * SS;
        }
        dbu = bdn[d] * SS;
    }

    // ---- state ----
    float cm1 = 0.f, cm2 = 0.f;                  // scaled cell states (-log2e * c)
    float y4g[9], h2g[9];
#pragma unroll
    for (int k = 0; k < 9; ++k) { y4g[k] = 0.f; h2g[k] = 0.f; }

    const float* xp0 = x + ((size_t)b * SEQT + t0) * 6 + 2 * p;
    float*       op  = out + ((size_t)b * SEQT + t_start) * 3 + u;

    // depth-2 prefetch ring (chunk length >= 102, so +12 is safe)
    float2 xv0 = *(const float2*)(xp0);
    float2 xv1 = *(const float2*)(xp0 + 6);
    const float* xpf = xp0 + 12;

#pragma unroll 2
    for (int t = t0; t < t_end; ++t) {
        // prefetch x for t+2 (pointer freezes near chunk end)
        const float2 xn = *(const float2*)(xpf);
        xpf += ((t + 3) < t_end) ? 6 : 0;

        // ---- LSTM-1 (slots 0..2 are this lane's branch h); pk_fma pairs ----
        f32x2 zA = b1p[0], zB = b1p[1];
        zA += w1a[0] * xv0.x;    zB += w1a[1] * xv0.x;
        zA += w1b[0] * xv0.y;    zB += w1b[1] * xv0.y;
        zA += w1h[0][0] * y4g[0]; zB += w1h[1][0] * y4g[0];
        zA += w1h[0][1] * y4g[1]; zB += w1h[1][1] * y4g[1];
        zA += w1h[0][2] * y4g[2]; zB += w1h[1][2] * y4g[2];
        {
            const float eI = fexp2(zA.x), eF = fexp2(zA.y);
            const float eG = fexp2(zB.x), eO = fexp2(zB.y);
            const float f   = frcp(1.0f + eF);
            const float pig = (1.0f + eI) * (1.0f + eG);
            cm1 = f * cm1 + frcp(-0.69314718056f * pig);
            const float ec = fexp2(cm1);
            const float h1v = frcp((1.0f + eO) * (1.0f + ec));

            // ---- issue y4 gathers immediately (rotated order) ----
#pragma unroll
            for (int k = 0; k < 9; ++k) y4g[k] = bperm(offv[k], h1v);
        }

        // ---- dense + store for step t-1 (old h2g; fills DS window) ----
        if (t > t_start) {
            float a0 = dbu, a1 = 0.f;
#pragma unroll
            for (int k = 0; k < 4; ++k) a0 += h2g[k] * wdk[k];
#pragma unroll
            for (int k = 4; k < 9; ++k) a1 += h2g[k] * wdk[k];
            const float yv = frcp(1.0f + fexp2(a0 + a1));
            if (do_store) *op = yv;
            op += 3;
        }

        // ---- zh: LSTM2 h-recurrence partials (old h2g; fills DS window) ----
        f32x2 zhA = b2p[0], zhB = b2p[1];
        f32x2 zhA1 = (f32x2)(0.f), zhB1 = (f32x2)(0.f);
#pragma unroll
        for (int k = 0; k < 4; ++k) { zhA  += w2hp[0][k] * h2g[k]; zhB  += w2hp[1][k] * h2g[k]; }
#pragma unroll
        for (int k = 4; k < 9; ++k) { zhA1 += w2hp[0][k] * h2g[k]; zhB1 += w2hp[1][k] * h2g[k]; }
        zhA += zhA1; zhB += zhB1;

        // ---- finish LSTM2 (waits on y4 gathers here) ----
        f32x2 z2A = zhA, z2B = zhB;
        f32x2 z2A1 = (f32x2)(0.f), z2B1 = (f32x2)(0.f);
#pragma unroll
        for (int k = 0; k < 4; ++k) { z2A  += w2xp[0][k] * y4g[k]; z2B  += w2xp[1][k] * y4g[k]; }
#pragma unroll
        for (int k = 4; k < 9; ++k) { z2A1 += w2xp[0][k] * y4g[k]; z2B1 += w2xp[1][k] * y4g[k]; }
        z2A += z2A1; z2B += z2B1;
        {
            const float eI = fexp2(z2A.x), eF = fexp2(z2A.y);
            const float eG = fexp2(z2B.x), eO = fexp2(z2B.y);
            const float f   = frcp(1.0f + eF);
            const float pig = (1.0f + eI) * (1.0f + eG);
            cm2 = f * cm2 + frcp(-0.69314718056f * pig);
            const float ec = fexp2(cm2);
            const float h2v = frcp((1.0f + eO) * (1.0f + ec));

            // ---- issue h2 gathers immediately ----
#pragma unroll
            for (int k = 0; k < 9; ++k) h2g[k] = bperm(offv[k], h2v);
        }

        xv0 = xv1; xv1 = xn;
    }

    // ---- epilogue: dense + store for final step (t_end-1) ----
    {
        float a0 = dbu, a1 = 0.f;
#pragma unroll
        for (int k = 0; k < 4; ++k) a0 += h2g[k] * wdk[k];
#pragma unroll
        for (int k = 4; k < 9; ++k) a1 += h2g[k] * wdk[k];
        const float yv = frcp(1.0f + fexp2(a0 + a1));
        if (do_store) *op = yv;
    }
}

extern "C" void kernel_launch(void* const* d_in, const int* in_sizes, int n_in,
                              void* d_out, int out_size, void* d_ws, size_t ws_size,
                              hipStream_t stream) {
    (void)in_sizes; (void)n_in; (void)d_ws; (void)ws_size; (void)out_size;
    const int blocks = (KC * WPC) / 4;   // 2940 waves = 735 blocks x 4 waves (exact)
    hipLaunchKernelGGL(fused_lstm3, dim3(blocks), dim3(256), 0, stream,
                       (const float*)d_in[0],
                       (const float*)d_in[1], (const float*)d_in[2], (const float*)d_in[3],
                       (const float*)d_in[4], (const float*)d_in[5], (const float*)d_in[6],
                       (const float*)d_in[7], (const float*)d_in[8],
                       (float*)d_out);
}

// Round 6
// 240.162 us; speedup vs baseline: 4.1119x; 1.0095x over previous
//
#include <hip/hip_runtime.h>

// Fused 3-branch shared LSTM(H1=3) -> LSTM(H2=9) -> dense(3)+sigmoid, T=2048, B=1024.
// 9 lanes per chain (lane u: LSTM1 unit (u/3,u%3), LSTM2 unit u), 7 chains/wave.
// Weights in VGPRs pre-scaled by -log2(e); merged-rcp sigmoid cells; scaled cell state.
// Rotated gather order (slot k = unit (3p+k)%9) so slots 0..2 are own-branch h.
// R6: amdgpu_waves_per_eu(3,3) pins occupancy AND register budget (~170) so the
// ~160-reg working set stays in arch VGPRs (no accvgpr shuttling); 32-bit offsets.

#define BATCH  1024
#define SEQT   2048
#define KC     20
#define WPC    147    // ceil(1024/7) waves per chunk slot
#define WARMUP 64

typedef float f32x2 __attribute__((ext_vector_type(2)));

__device__ __forceinline__ float fexp2(float v) { return __builtin_amdgcn_exp2f(v); }
__device__ __forceinline__ float frcp(float v)  { return __builtin_amdgcn_rcpf(v); }
__device__ __forceinline__ float bperm(int addr, float v) {
    return __int_as_float(__builtin_amdgcn_ds_bpermute(addr, __float_as_int(v)));
}

__global__ __launch_bounds__(256) __attribute__((amdgpu_waves_per_eu(3, 3)))
void fused_lstm3(const float* __restrict__ x,
                 const float* __restrict__ wk1, const float* __restrict__ wr1,
                 const float* __restrict__ b1,
                 const float* __restrict__ wk2, const float* __restrict__ wr2,
                 const float* __restrict__ b2,
                 const float* __restrict__ wdn, const float* __restrict__ bdn,
                 float* __restrict__ out)
{
    const int lane  = threadIdx.x & 63;
    const int wavei = threadIdx.x >> 6;
    const int group = lane / 9;                  // 7 groups of 9 lanes; lane 63 idle
    const bool act  = (group < 7);
    const int u     = act ? (lane - group * 9) : 0;

    const int wv = blockIdx.x * 4 + wavei;
    int s        = wv / WPC;
    const int bw = wv - s * WPC;
    const bool vs = (s < KC);
    if (!vs) s = KC - 1;
    int b = bw * 7 + (act ? group : 6);
    const bool vb = (b < BATCH);
    if (!vb) b = BATCH - 1;
    const bool do_store = vs && vb && act && (u < 3);

    const int t_start = (SEQT * s) / KC;
    const int t_end   = (SEQT * (s + 1)) / KC;
    const int t0      = (t_start > WARMUP) ? (t_start - WARMUP) : 0;

    const int p  = u / 3;                        // branch index
    const int q  = u - p * 3;                    // unit within branch

    const float SS = -1.44269504088896f;         // -log2(e) folded into gate weights

    // rotated gather addresses: slot k <- unit (3p+k)%9 of this group
    int offv[9];
#pragma unroll
    for (int k = 0; k < 9; ++k) {
        int j = 3 * p + k; j = (j >= 9) ? j - 9 : j;
        offv[k] = (group * 9 + j) << 2;
    }

    // ---- per-lane weights, pre-scaled, packed in gate-pairs (i,f) and (g,o) ----
    f32x2 w1a[2], w1b[2], w1h[2][3], b1p[2];
    f32x2 w2xp[2][9], w2hp[2][9], b2p[2];
    float wdk[9], dbu;
#pragma unroll
    for (int pr = 0; pr < 2; ++pr) {
        const int g0 = 2 * pr, g1 = 2 * pr + 1;
        const int c0 = g0 * 3 + q, c1 = g1 * 3 + q;      // LSTM1 cols (gate-major i,f,g,o)
        w1a[pr].x = wk1[c0] * SS;       w1a[pr].y = wk1[c1] * SS;
        w1b[pr].x = wk1[12 + c0] * SS;  w1b[pr].y = wk1[12 + c1] * SS;
#pragma unroll
        for (int k = 0; k < 3; ++k) {
            w1h[pr][k].x = wr1[k * 12 + c0] * SS;
            w1h[pr][k].y = wr1[k * 12 + c1] * SS;
        }
        b1p[pr].x = b1[c0] * SS;  b1p[pr].y = b1[c1] * SS;
        const int d0 = g0 * 9 + u, d1 = g1 * 9 + u;      // LSTM2 cols
#pragma unroll
        for (int k = 0; k < 9; ++k) {
            const int jj = (offv[k] >> 2) - group * 9;   // permuted unit index
            w2xp[pr][k].x = wk2[jj * 36 + d0] * SS;
            w2xp[pr][k].y = wk2[jj * 36 + d1] * SS;
            w2hp[pr][k].x = wr2[jj * 36 + d0] * SS;
            w2hp[pr][k].y = wr2[jj * 36 + d1] * SS;
        }
        b2p[pr].x = b2[d0] * SS;  b2p[pr].y = b2[d1] * SS;
    }
    {
        const int d = (u < 3) ? u : 0;
#pragma unroll
        for (int k = 0; k < 9; ++k) {
            const int jj = (offv[k] >> 2) - group * 9;
            wdk[k] = wdn[jj * 3 + d] * SS;
        }
        dbu = bdn[d] * SS;
    }

    // ---- state ----
    float cm1 = 0.f, cm2 = 0.f;                  // scaled cell states (-log2e * c)
    float y4g[9], h2g[9];
#pragma unroll
    for (int k = 0; k < 9; ++k) { y4g[k] = 0.f; h2g[k] = 0.f; }

    // 32-bit element offsets from SGPR bases (x = 48 MB, out = 25 MB: both < 4 GB)
    int xo = (b * SEQT + t0) * 6 + 2 * p;
    int oo = (b * SEQT + t_start) * 3 + u;

    // depth-2 prefetch ring (chunk length >= 102, so +12 is safe)
    float2 xv0 = *(const float2*)(x + xo);
    float2 xv1 = *(const float2*)(x + xo + 6);
    xo += 12;

#pragma unroll 2
    for (int t = t0; t < t_end; ++t) {
        // prefetch x for t+2 (offset freezes near chunk end)
        const float2 xn = *(const float2*)(x + xo);
        xo += ((t + 3) < t_end) ? 6 : 0;

        // ---- LSTM-1 (slots 0..2 are this lane's branch h); pk_fma pairs ----
        f32x2 zA = b1p[0], zB = b1p[1];
        zA += w1a[0] * xv0.x;    zB += w1a[1] * xv0.x;
        zA += w1b[0] * xv0.y;    zB += w1b[1] * xv0.y;
        zA += w1h[0][0] * y4g[0]; zB += w1h[1][0] * y4g[0];
        zA += w1h[0][1] * y4g[1]; zB += w1h[1][1] * y4g[1];
        zA += w1h[0][2] * y4g[2]; zB += w1h[1][2] * y4g[2];
        {
            const float eI = fexp2(zA.x), eF = fexp2(zA.y);
            const float eG = fexp2(zB.x), eO = fexp2(zB.y);
            const float f   = frcp(1.0f + eF);
            const float pig = (1.0f + eI) * (1.0f + eG);
            cm1 = f * cm1 + frcp(-0.69314718056f * pig);
            const float ec = fexp2(cm1);
            const float h1v = frcp((1.0f + eO) * (1.0f + ec));

            // ---- issue y4 gathers immediately (rotated order) ----
#pragma unroll
            for (int k = 0; k < 9; ++k) y4g[k] = bperm(offv[k], h1v);
        }

        // ---- dense + store for step t-1 (old h2g; fills DS window) ----
        if (t > t_start) {
            float a0 = dbu, a1 = 0.f;
#pragma unroll
            for (int k = 0; k < 4; ++k) a0 += h2g[k] * wdk[k];
#pragma unroll
            for (int k = 4; k < 9; ++k) a1 += h2g[k] * wdk[k];
            const float yv = frcp(1.0f + fexp2(a0 + a1));
            if (do_store) out[oo] = yv;
            oo += 3;
        }

        // ---- zh: LSTM2 h-recurrence partials (old h2g; fills DS window) ----
        f32x2 zhA = b2p[0], zhB = b2p[1];
        f32x2 zhA1 = (f32x2)(0.f), zhB1 = (f32x2)(0.f);
#pragma unroll
        for (int k = 0; k < 4; ++k) { zhA  += w2hp[0][k] * h2g[k]; zhB  += w2hp[1][k] * h2g[k]; }
#pragma unroll
        for (int k = 4; k < 9; ++k) { zhA1 += w2hp[0][k] * h2g[k]; zhB1 += w2hp[1][k] * h2g[k]; }
        zhA += zhA1; zhB += zhB1;

        // ---- finish LSTM2 (waits on y4 gathers here) ----
        f32x2 z2A = zhA, z2B = zhB;
        f32x2 z2A1 = (f32x2)(0.f), z2B1 = (f32x2)(0.f);
#pragma unroll
        for (int k = 0; k < 4; ++k) { z2A  += w2xp[0][k] * y4g[k]; z2B  += w2xp[1][k] * y4g[k]; }
#pragma unroll
        for (int k = 4; k < 9; ++k) { z2A1 += w2xp[0][k] * y4g[k]; z2B1 += w2xp[1][k] * y4g[k]; }
        z2A += z2A1; z2B += z2B1;
        {
            const float eI = fexp2(z2A.x), eF = fexp2(z2A.y);
            const float eG = fexp2(z2B.x), eO = fexp2(z2B.y);
            const float f   = frcp(1.0f + eF);
            const float pig = (1.0f + eI) * (1.0f + eG);
            cm2 = f * cm2 + frcp(-0.69314718056f * pig);
            const float ec = fexp2(cm2);
            const float h2v = frcp((1.0f + eO) * (1.0f + ec));

            // ---- issue h2 gathers immediately ----
#pragma unroll
            for (int k = 0; k < 9; ++k) h2g[k] = bperm(offv[k], h2v);
        }

        xv0 = xv1; xv1 = xn;
    }

    // ---- epilogue: dense + store for final step (t_end-1) ----
    {
        float a0 = dbu, a1 = 0.f;
#pragma unroll
        for (int k = 0; k < 4; ++k) a0 += h2g[k] * wdk[k];
#pragma unroll
        for (int k = 4; k < 9; ++k) a1 += h2g[k] * wdk[k];
        const float yv = frcp(1.0f + fexp2(a0 + a1));
        if (do_store) out[oo] = yv;
    }
}

extern "C" void kernel_launch(void* const* d_in, const int* in_sizes, int n_in,
                              void* d_out, int out_size, void* d_ws, size_t ws_size,
                              hipStream_t stream) {
    (void)in_sizes; (void)n_in; (void)d_ws; (void)ws_size; (void)out_size;
    const int blocks = (KC * WPC) / 4;   // 2940 waves = 735 blocks x 4 waves (exact)
    hipLaunchKernelGGL(fused_lstm3, dim3(blocks), dim3(256), 0, stream,
                       (const float*)d_in[0],
                       (const float*)d_in[1], (const float*)d_in[2], (const float*)d_in[3],
                       (const float*)d_in[4], (const float*)d_in[5], (const float*)d_in[6],
                       (const float*)d_in[7], (const float*)d_in[8],
                       (float*)d_out);
}